// Round 5
// baseline (454.881 us; speedup 1.0000x reference)
//
#include <hip/hip_runtime.h>
#include <hip/hip_bf16.h>
#include <math.h>

#define N_ENT 150000
#define N_REL 500
#define H     128
#define DEG   32
#define TOPK  10

typedef unsigned short ushort_t;
typedef unsigned int   uint_t;
typedef __attribute__((ext_vector_type(8))) short short8;
typedef __attribute__((ext_vector_type(4))) float f32x4;
typedef __attribute__((ext_vector_type(2))) float f32x2;

__device__ inline ushort_t f2bf(float x) {
    __hip_bfloat16 h = __float2bfloat16(x);   // RNE
    return *reinterpret_cast<ushort_t*>(&h);
}
__device__ inline float bf2f(ushort_t u) {
    uint_t v = ((uint_t)u) << 16;
    return *reinterpret_cast<float*>(&v);
}
// unpack 2 bf16 (packed in one u32) -> 2 f32: {low ushort, high ushort}
__device__ inline f32x2 unpk2(uint_t u) {
    uint_t lo = u << 16;
    uint_t hi = u & 0xFFFF0000u;
    f32x2 r;
    r.x = *reinterpret_cast<float*>(&lo);
    r.y = *reinterpret_cast<float*>(&hi);
    return r;
}
__device__ inline float dot4(float4 a, float4 b) {
    return a.x * b.x + a.y * b.y + a.z * b.z + a.w * b.w;
}
__device__ inline float fast_tanh(float x) {
    float e = __expf(2.f * x);                 // v_exp_f32
    return 1.f - 2.f * __builtin_amdgcn_rcpf(e + 1.f);
}

// ---------------------------------------------------------------------------
// Kernel A: tiny precomputes.
// ---------------------------------------------------------------------------
__global__ __launch_bounds__(128) void precompute_small(
    const float* __restrict__ W, const float* __restrict__ Wr,
    const float* __restrict__ nw, const float* __restrict__ a,
    float* __restrict__ M, float* __restrict__ M2,
    float* __restrict__ v1, float* __restrict__ v2, float* __restrict__ u3)
{
    int j = threadIdx.x;
    if (blockIdx.x < H) {
        int r = blockIdx.x;
        float m = 0.f, m2 = 0.f;
        for (int t = 0; t < H; ++t) {
            float x = nw[t * H + j];
            m  += W [r * H + t] * x;
            m2 += Wr[r * H + t] * x;
        }
        M [r * H + j] = m;
        M2[r * H + j] = m2;
    } else {
        int h = j;
        float s1 = 0.f, s2 = 0.f, s3 = 0.f;
        for (int t = 0; t < H; ++t) {
            s1 += W [h * H + t] * a[t];
            s2 += W [h * H + t] * a[H + t];
            s3 += Wr[h * H + t] * a[2 * H + t];
        }
        v1[h] = s1; v2[h] = s2; u3[h] = s3;
    }
}

// ---------------------------------------------------------------------------
// Kernel A2: build B fragments of M in MFMA lane layout, bf16 hi/lo.
// ---------------------------------------------------------------------------
__global__ __launch_bounds__(64) void bfrag_build(
    const float* __restrict__ M, ushort_t* __restrict__ Bhi,
    ushort_t* __restrict__ Blo)
{
    int b = blockIdx.x;           // 0..31 = c*4 + t
    int c = b >> 2, tt = b & 3;
    int l = threadIdx.x;
    int n  = c * 16 + (l & 15);
    int k0 = tt * 32 + (l >> 4) * 8;
    #pragma unroll
    for (int j = 0; j < 8; ++j) {
        float x = M[(k0 + j) * H + n];
        ushort_t h = f2bf(x);
        Bhi[(size_t)(b * 64 + l) * 8 + j] = h;
        Blo[(size_t)(b * 64 + l) * 8 + j] = f2bf(x - bf2f(h));
    }
}

// ---------------------------------------------------------------------------
// Kernel B: R = rel_emb @ M2 (500x128, bf16), s_rel = rel_emb @ u3
// ---------------------------------------------------------------------------
__global__ __launch_bounds__(128) void rel_transform(
    const float* __restrict__ rel, const float* __restrict__ M2,
    const float* __restrict__ u3, ushort_t* __restrict__ Rb,
    float* __restrict__ srel)
{
    __shared__ float red[H];
    int r = blockIdx.x, j = threadIdx.x;
    float acc = 0.f;
    for (int h = 0; h < H; ++h)
        acc += rel[r * H + h] * M2[h * H + j];
    Rb[r * H + j] = f2bf(acc);
    red[j] = rel[r * H + j] * u3[j];
    __syncthreads();
    for (int s = 64; s > 0; s >>= 1) {
        if (j < s) red[j] += red[j + s];
        __syncthreads();
    }
    if (j == 0) srel[r] = red[0];
}

// ---------------------------------------------------------------------------
// Kernel C v4: G = ent @ M via bf16 hi/lo MFMA, operand-swapped so the
// C-fragment is transposed: lane (quad,m) holds 4 consecutive h-cols
// of entity row (waveRow + s*16 + m).  Epilogue: 16x 8B stores/thread.
// (unchanged this round — waiting for it to surface in top-5 w/ counters)
// ---------------------------------------------------------------------------
__global__ __launch_bounds__(256) void ent_transform3(
    const float* __restrict__ ent, const ushort_t* __restrict__ Bhi,
    const ushort_t* __restrict__ Blo, const float* __restrict__ v1,
    const float* __restrict__ v2, ushort_t* __restrict__ Gb,
    float* __restrict__ ssrc, float* __restrict__ sdst)
{
    const int t    = threadIdx.x;
    const int w    = t >> 6;       // wave 0..3
    const int l    = t & 63;
    const int m    = l & 15;
    const int quad = l >> 4;
    const long blockRow = (long)blockIdx.x * 128;
    const long waveRow  = blockRow + (long)w * 32;

    float4 v1a[4], v1b[4], v2a[4], v2b[4];
    #pragma unroll
    for (int tt = 0; tt < 4; ++tt) {
        const float* p1 = v1 + tt * 32 + quad * 8;
        const float* p2 = v2 + tt * 32 + quad * 8;
        v1a[tt] = *(const float4*)p1; v1b[tt] = *(const float4*)(p1 + 4);
        v2a[tt] = *(const float4*)p2; v2b[tt] = *(const float4*)(p2 + 4);
    }

    short8 Ahi[2][4], Alo[2][4];
    float p1s[2] = {0.f, 0.f}, p2s[2] = {0.f, 0.f};
    #pragma unroll
    for (int s = 0; s < 2; ++s) {
        long row = waveRow + s * 16 + m;
        long rc  = row < N_ENT ? row : (N_ENT - 1);
        const float* rp = ent + rc * H;
        #pragma unroll
        for (int tt = 0; tt < 4; ++tt) {
            float4 e0 = *(const float4*)(rp + tt * 32 + quad * 8);
            float4 e1 = *(const float4*)(rp + tt * 32 + quad * 8 + 4);
            p1s[s] += dot4(e0, v1a[tt]) + dot4(e1, v1b[tt]);
            p2s[s] += dot4(e0, v2a[tt]) + dot4(e1, v2b[tt]);
            float x[8] = {e0.x, e0.y, e0.z, e0.w, e1.x, e1.y, e1.z, e1.w};
            #pragma unroll
            for (int j = 0; j < 8; ++j) {
                ushort_t h = f2bf(x[j]);
                Ahi[s][tt][j] = (short)h;
                Alo[s][tt][j] = (short)f2bf(x[j] - bf2f(h));
            }
        }
    }
    #pragma unroll
    for (int s = 0; s < 2; ++s) {
        p1s[s] += __shfl_xor(p1s[s], 16); p1s[s] += __shfl_xor(p1s[s], 32);
        p2s[s] += __shfl_xor(p2s[s], 16); p2s[s] += __shfl_xor(p2s[s], 32);
    }
    if (quad == 0) {
        #pragma unroll
        for (int s = 0; s < 2; ++s) {
            long row = waveRow + s * 16 + m;
            if (row < N_ENT) { ssrc[row] = p1s[s]; sdst[row] = p2s[s]; }
        }
    }

    for (int c = 0; c < 8; ++c) {
        short8 bh[4], bl[4];
        #pragma unroll
        for (int tt = 0; tt < 4; ++tt) {
            size_t off = (size_t)((c * 4 + tt) * 64 + l) * 8;
            bh[tt] = *(const short8*)(Bhi + off);
            bl[tt] = *(const short8*)(Blo + off);
        }
        f32x4 acc0 = {0.f, 0.f, 0.f, 0.f}, acc1 = {0.f, 0.f, 0.f, 0.f};
        #pragma unroll
        for (int tt = 0; tt < 4; ++tt) {
            acc0 = __builtin_amdgcn_mfma_f32_16x16x32_bf16(bh[tt], Ahi[0][tt], acc0, 0, 0, 0);
            acc0 = __builtin_amdgcn_mfma_f32_16x16x32_bf16(bh[tt], Alo[0][tt], acc0, 0, 0, 0);
            acc0 = __builtin_amdgcn_mfma_f32_16x16x32_bf16(bl[tt], Ahi[0][tt], acc0, 0, 0, 0);
            acc1 = __builtin_amdgcn_mfma_f32_16x16x32_bf16(bh[tt], Ahi[1][tt], acc1, 0, 0, 0);
            acc1 = __builtin_amdgcn_mfma_f32_16x16x32_bf16(bh[tt], Alo[1][tt], acc1, 0, 0, 0);
            acc1 = __builtin_amdgcn_mfma_f32_16x16x32_bf16(bl[tt], Ahi[1][tt], acc1, 0, 0, 0);
        }
        #pragma unroll
        for (int s = 0; s < 2; ++s) {
            f32x4 a = s ? acc1 : acc0;
            long row = waveRow + s * 16 + m;
            if (row < N_ENT) {
                ushort4 o;
                o.x = f2bf(a[0]); o.y = f2bf(a[1]);
                o.z = f2bf(a[2]); o.w = f2bf(a[3]);
                *(ushort4*)(Gb + (size_t)row * H + c * 16 + quad * 4) = o;
            }
        }
    }
}

// ---------------------------------------------------------------------------
// Kernel D v6: pipelined top-10, VGPR-slimmed for 8 waves/EU occupancy.
//  - __launch_bounds__(256, 8): cap VGPR at 64 (occupancy cliff per m69).
//  - pk[] array eliminated: broadcast shuffle result consumed immediately
//    for Gb/Rb address gen + load issue (loads start during the shuffle
//    sequence; allocator free to interleave accumulates to cap in-flight).
//  - Same cross-iteration prefetch (stage A: src/rid; stage B: score
//    gathers) as v5.  Numerics identical to v5.
// ---------------------------------------------------------------------------
__global__ __launch_bounds__(256, 8) void gather_topk_out(
    const int* __restrict__ src, const int* __restrict__ rel_id,
    const float* __restrict__ ssrc, const float* __restrict__ sdst,
    const float* __restrict__ srel, const ushort_t* __restrict__ Gb,
    const ushort_t* __restrict__ Rb, float* __restrict__ out)
{
    const int l         = threadIdx.x & 31;
    const int halfShift = threadIdx.x & 32;    // 0 or 32
    const uint_t tie1   = (uint_t)(31 - l);
    const ushort_t* GbL = Gb + l * 4;
    const ushort_t* RbL = Rb + l * 4;
    int hw  = (blockIdx.x * blockDim.x + threadIdx.x) >> 5;
    int nhw = (gridDim.x * blockDim.x) >> 5;

    int i = hw;
    if (i >= N_ENT) return;

    // pipeline prologue: stage A+B for first node
    int   sidx = src   [(size_t)i * DEG + l];
    int   ridx = rel_id[(size_t)i * DEG + l];
    float s1 = ssrc[sidx], s2 = sdst[i], s3 = srel[ridx];

    while (true) {
        const int inext = i + nhw;
        const int ic    = inext < N_ENT ? inext : i;   // clamped prefetch idx

        // ---- stage A(i+1): issue coalesced index loads early ----
        const size_t off2 = (size_t)ic * DEG + l;
        int sidx2 = src[off2];
        int ridx2 = rel_id[off2];

        // ---- current node: score + monotone key ----
        float x   = s1 + s2 + s3;
        float val = x >= 0.f ? x : 0.2f * x;           // leaky_relu(0.2)
        uint_t ub = __builtin_bit_cast(uint_t, val);
        uint_t mk = ub ^ (uint_t)(((int)ub >> 31) | (int)0x80000000);
        unsigned long long k1 = ((unsigned long long)mk << 5) | tie1;

        // ---- rank phase (31 shuffles) — hides stage-A latency ----
        int rank = 0;
        #pragma unroll
        for (int xm = 1; xm < 32; ++xm) {
            uint_t mk2 = (uint_t)__shfl_xor((int)mk, xm, 32);
            unsigned long long k2 =
                ((unsigned long long)mk2 << 5) | (tie1 ^ (uint_t)xm);
            rank += (k2 > k1) ? 1 : 0;
        }
        bool sel = rank < TOPK;

        // ---- stage B(i+1): issue dependent score gathers ----
        float s1n = ssrc[sidx2];
        float s2n = sdst[ic];
        float s3n = srel[ridx2];

        // ---- global max = rank-0 lane's value ----
        unsigned long long b0 = __ballot(rank == 0);
        int l0 = (int)__builtin_ctz((uint_t)(b0 >> halfShift));
        float mx = __shfl(val, l0, 32);

        float e = sel ? __expf(val - mx) : 0.f;

        // selected-lane mask for this half-wave
        unsigned long long ball = __ballot(sel);
        uint_t mask = (uint_t)(ball >> halfShift);

        // broadcast + load-issue fused: packed idx consumed immediately,
        // never stored (saves 10 VGPR vs pk[] array)
        uint_t packed = (uint_t)sidx | ((uint_t)ridx << 18);
        uint2 gv[TOPK], rv[TOPK]; float wk[TOPK];
        #pragma unroll
        for (int k = 0; k < TOPK; ++k) {
            int lk = (int)__builtin_ctz(mask); mask &= mask - 1;
            uint_t p = (uint_t)__shfl((int)packed, lk, 32);
            wk[k] = __shfl(e, lk, 32);
            gv[k] = *(const uint2*)(GbL + (size_t)(p & 0x3FFFF) * H);
            rv[k] = *(const uint2*)(RbL + (size_t)(p >> 18) * H);
        }
        float ws = ((wk[0] + wk[1]) + (wk[2] + wk[3]))
                 + ((wk[4] + wk[5]) + (wk[6] + wk[7]))
                 + (wk[8] + wk[9]);
        float rnorm = __builtin_amdgcn_rcpf(ws);

        f32x2 a01 = {0.f, 0.f}, a23 = {0.f, 0.f};
        #pragma unroll
        for (int k = 0; k < TOPK; ++k) {
            float wv = wk[k];
            f32x2 g01 = unpk2(gv[k].x), g23 = unpk2(gv[k].y);
            f32x2 r01 = unpk2(rv[k].x), r23 = unpk2(rv[k].y);
            a01 += (g01 + r01) * wv;
            a23 += (g23 + r23) * wv;
        }
        a01 *= rnorm; a23 *= rnorm;

        float4 o;
        o.x = fast_tanh(a01.x); o.y = fast_tanh(a01.y);
        o.z = fast_tanh(a23.x); o.w = fast_tanh(a23.y);
        ((float4*)(out + (size_t)i * H))[l] = o;

        if (inext >= N_ENT) break;
        i = inext;
        sidx = sidx2; ridx = ridx2;
        s1 = s1n; s2 = s2n; s3 = s3n;
    }
}

// ---------------------------------------------------------------------------
extern "C" void kernel_launch(void* const* d_in, const int* in_sizes, int n_in,
                              void* d_out, int out_size, void* d_ws, size_t ws_size,
                              hipStream_t stream) {
    const float* ent = (const float*)d_in[0];   // 150000x128
    const float* rel = (const float*)d_in[1];   // 500x128
    const float* W   = (const float*)d_in[2];   // 128x128
    const float* Wr  = (const float*)d_in[3];   // 128x128
    const float* a   = (const float*)d_in[4];   // 384
    const float* nw  = (const float*)d_in[5];   // 128x128
    const int*   src = (const int*)d_in[6];     // 150000x32
    const int*   rid = (const int*)d_in[7];     // 150000x32
    float* out = (float*)d_out;                 // 150000x128

    float* ws = (float*)d_ws;
    float*    M    = ws;                     // 16384
    float*    M2   = M    + 16384;           // 16384
    float*    v1   = M2   + 16384;           // 128
    float*    v2   = v1   + 128;             // 128
    float*    u3   = v2   + 128;             // 128
    float*    srel = u3   + 128;             // 512 (padded)
    float*    ssrc = srel + 512;             // 150016
    float*    sdst = ssrc + 150016;          // 150016
    ushort_t* Bhi  = (ushort_t*)(sdst + 150016);            // 16384 bf16
    ushort_t* Blo  = Bhi + 16384;                           // 16384 bf16
    ushort_t* Rb   = Blo + 16384;                           // 64000 bf16
    ushort_t* Gb   = Rb  + 64000;                           // 19.2M bf16

    precompute_small<<<H + 1, H, 0, stream>>>(W, Wr, nw, a, M, M2, v1, v2, u3);
    bfrag_build    <<<32, 64, 0, stream>>>(M, Bhi, Blo);
    rel_transform  <<<N_REL, H, 0, stream>>>(rel, M2, u3, Rb, srel);
    ent_transform3 <<<(N_ENT + 127) / 128, 256, 0, stream>>>(ent, Bhi, Blo,
                                                             v1, v2, Gb, ssrc, sdst);
    gather_topk_out<<<2048, 256, 0, stream>>>(src, rid, ssrc, sdst, srel,
                                              Gb, Rb, out);
}

// Round 6
// 334.002 us; speedup vs baseline: 1.3619x; 1.3619x over previous
//
#include <hip/hip_runtime.h>
#include <hip/hip_bf16.h>
#include <math.h>

#define N_ENT 150000
#define N_REL 500
#define H     128
#define DEG   32
#define TOPK  10

typedef unsigned short ushort_t;
typedef unsigned int   uint_t;
typedef __attribute__((ext_vector_type(8))) short short8;
typedef __attribute__((ext_vector_type(4))) float f32x4;
typedef __attribute__((ext_vector_type(2))) float f32x2;

__device__ inline ushort_t f2bf(float x) {
    __hip_bfloat16 h = __float2bfloat16(x);   // RNE
    return *reinterpret_cast<ushort_t*>(&h);
}
__device__ inline float bf2f(ushort_t u) {
    uint_t v = ((uint_t)u) << 16;
    return *reinterpret_cast<float*>(&v);
}
// unpack 2 bf16 (packed in one u32) -> 2 f32: {low ushort, high ushort}
__device__ inline f32x2 unpk2(uint_t u) {
    uint_t lo = u << 16;
    uint_t hi = u & 0xFFFF0000u;
    f32x2 r;
    r.x = *reinterpret_cast<float*>(&lo);
    r.y = *reinterpret_cast<float*>(&hi);
    return r;
}
__device__ inline float dot4(float4 a, float4 b) {
    return a.x * b.x + a.y * b.y + a.z * b.z + a.w * b.w;
}
__device__ inline float fast_tanh(float x) {
    float e = __expf(2.f * x);                 // v_exp_f32
    return 1.f - 2.f * __builtin_amdgcn_rcpf(e + 1.f);
}

// ---------------------------------------------------------------------------
// Kernel A: tiny precomputes.
// ---------------------------------------------------------------------------
__global__ __launch_bounds__(128) void precompute_small(
    const float* __restrict__ W, const float* __restrict__ Wr,
    const float* __restrict__ nw, const float* __restrict__ a,
    float* __restrict__ M, float* __restrict__ M2,
    float* __restrict__ v1, float* __restrict__ v2, float* __restrict__ u3)
{
    int j = threadIdx.x;
    if (blockIdx.x < H) {
        int r = blockIdx.x;
        float m = 0.f, m2 = 0.f;
        for (int t = 0; t < H; ++t) {
            float x = nw[t * H + j];
            m  += W [r * H + t] * x;
            m2 += Wr[r * H + t] * x;
        }
        M [r * H + j] = m;
        M2[r * H + j] = m2;
    } else {
        int h = j;
        float s1 = 0.f, s2 = 0.f, s3 = 0.f;
        for (int t = 0; t < H; ++t) {
            s1 += W [h * H + t] * a[t];
            s2 += W [h * H + t] * a[H + t];
            s3 += Wr[h * H + t] * a[2 * H + t];
        }
        v1[h] = s1; v2[h] = s2; u3[h] = s3;
    }
}

// ---------------------------------------------------------------------------
// Kernel A2: build B fragments of M in MFMA lane layout, bf16 hi/lo.
// ---------------------------------------------------------------------------
__global__ __launch_bounds__(64) void bfrag_build(
    const float* __restrict__ M, ushort_t* __restrict__ Bhi,
    ushort_t* __restrict__ Blo)
{
    int b = blockIdx.x;           // 0..31 = c*4 + t
    int c = b >> 2, tt = b & 3;
    int l = threadIdx.x;
    int n  = c * 16 + (l & 15);
    int k0 = tt * 32 + (l >> 4) * 8;
    #pragma unroll
    for (int j = 0; j < 8; ++j) {
        float x = M[(k0 + j) * H + n];
        ushort_t h = f2bf(x);
        Bhi[(size_t)(b * 64 + l) * 8 + j] = h;
        Blo[(size_t)(b * 64 + l) * 8 + j] = f2bf(x - bf2f(h));
    }
}

// ---------------------------------------------------------------------------
// Kernel B: R = rel_emb @ M2 (500x128, bf16), s_rel = rel_emb @ u3
// ---------------------------------------------------------------------------
__global__ __launch_bounds__(128) void rel_transform(
    const float* __restrict__ rel, const float* __restrict__ M2,
    const float* __restrict__ u3, ushort_t* __restrict__ Rb,
    float* __restrict__ srel)
{
    __shared__ float red[H];
    int r = blockIdx.x, j = threadIdx.x;
    float acc = 0.f;
    for (int h = 0; h < H; ++h)
        acc += rel[r * H + h] * M2[h * H + j];
    Rb[r * H + j] = f2bf(acc);
    red[j] = rel[r * H + j] * u3[j];
    __syncthreads();
    for (int s = 64; s > 0; s >>= 1) {
        if (j < s) red[j] += red[j + s];
        __syncthreads();
    }
    if (j == 0) srel[r] = red[0];
}

// ---------------------------------------------------------------------------
// Kernel C v4: G = ent @ M via bf16 hi/lo MFMA, operand-swapped so the
// C-fragment is transposed: lane (quad,m) holds 4 consecutive h-cols
// of entity row (waveRow + s*16 + m).  Epilogue: 16x 8B stores/thread.
// ---------------------------------------------------------------------------
__global__ __launch_bounds__(256) void ent_transform3(
    const float* __restrict__ ent, const ushort_t* __restrict__ Bhi,
    const ushort_t* __restrict__ Blo, const float* __restrict__ v1,
    const float* __restrict__ v2, ushort_t* __restrict__ Gb,
    float* __restrict__ ssrc, float* __restrict__ sdst)
{
    const int t    = threadIdx.x;
    const int w    = t >> 6;       // wave 0..3
    const int l    = t & 63;
    const int m    = l & 15;
    const int quad = l >> 4;
    const long blockRow = (long)blockIdx.x * 128;
    const long waveRow  = blockRow + (long)w * 32;

    float4 v1a[4], v1b[4], v2a[4], v2b[4];
    #pragma unroll
    for (int tt = 0; tt < 4; ++tt) {
        const float* p1 = v1 + tt * 32 + quad * 8;
        const float* p2 = v2 + tt * 32 + quad * 8;
        v1a[tt] = *(const float4*)p1; v1b[tt] = *(const float4*)(p1 + 4);
        v2a[tt] = *(const float4*)p2; v2b[tt] = *(const float4*)(p2 + 4);
    }

    short8 Ahi[2][4], Alo[2][4];
    float p1s[2] = {0.f, 0.f}, p2s[2] = {0.f, 0.f};
    #pragma unroll
    for (int s = 0; s < 2; ++s) {
        long row = waveRow + s * 16 + m;
        long rc  = row < N_ENT ? row : (N_ENT - 1);
        const float* rp = ent + rc * H;
        #pragma unroll
        for (int tt = 0; tt < 4; ++tt) {
            float4 e0 = *(const float4*)(rp + tt * 32 + quad * 8);
            float4 e1 = *(const float4*)(rp + tt * 32 + quad * 8 + 4);
            p1s[s] += dot4(e0, v1a[tt]) + dot4(e1, v1b[tt]);
            p2s[s] += dot4(e0, v2a[tt]) + dot4(e1, v2b[tt]);
            float x[8] = {e0.x, e0.y, e0.z, e0.w, e1.x, e1.y, e1.z, e1.w};
            #pragma unroll
            for (int j = 0; j < 8; ++j) {
                ushort_t h = f2bf(x[j]);
                Ahi[s][tt][j] = (short)h;
                Alo[s][tt][j] = (short)f2bf(x[j] - bf2f(h));
            }
        }
    }
    #pragma unroll
    for (int s = 0; s < 2; ++s) {
        p1s[s] += __shfl_xor(p1s[s], 16); p1s[s] += __shfl_xor(p1s[s], 32);
        p2s[s] += __shfl_xor(p2s[s], 16); p2s[s] += __shfl_xor(p2s[s], 32);
    }
    if (quad == 0) {
        #pragma unroll
        for (int s = 0; s < 2; ++s) {
            long row = waveRow + s * 16 + m;
            if (row < N_ENT) { ssrc[row] = p1s[s]; sdst[row] = p2s[s]; }
        }
    }

    for (int c = 0; c < 8; ++c) {
        short8 bh[4], bl[4];
        #pragma unroll
        for (int tt = 0; tt < 4; ++tt) {
            size_t off = (size_t)((c * 4 + tt) * 64 + l) * 8;
            bh[tt] = *(const short8*)(Bhi + off);
            bl[tt] = *(const short8*)(Blo + off);
        }
        f32x4 acc0 = {0.f, 0.f, 0.f, 0.f}, acc1 = {0.f, 0.f, 0.f, 0.f};
        #pragma unroll
        for (int tt = 0; tt < 4; ++tt) {
            acc0 = __builtin_amdgcn_mfma_f32_16x16x32_bf16(bh[tt], Ahi[0][tt], acc0, 0, 0, 0);
            acc0 = __builtin_amdgcn_mfma_f32_16x16x32_bf16(bh[tt], Alo[0][tt], acc0, 0, 0, 0);
            acc0 = __builtin_amdgcn_mfma_f32_16x16x32_bf16(bl[tt], Ahi[0][tt], acc0, 0, 0, 0);
            acc1 = __builtin_amdgcn_mfma_f32_16x16x32_bf16(bh[tt], Ahi[1][tt], acc1, 0, 0, 0);
            acc1 = __builtin_amdgcn_mfma_f32_16x16x32_bf16(bh[tt], Alo[1][tt], acc1, 0, 0, 0);
            acc1 = __builtin_amdgcn_mfma_f32_16x16x32_bf16(bl[tt], Ahi[1][tt], acc1, 0, 0, 0);
        }
        #pragma unroll
        for (int s = 0; s < 2; ++s) {
            f32x4 a = s ? acc1 : acc0;
            long row = waveRow + s * 16 + m;
            if (row < N_ENT) {
                ushort4 o;
                o.x = f2bf(a[0]); o.y = f2bf(a[1]);
                o.z = f2bf(a[2]); o.w = f2bf(a[3]);
                *(ushort4*)(Gb + (size_t)row * H + c * 16 + quad * 4) = o;
            }
        }
    }
}

// ---------------------------------------------------------------------------
// Kernel D v7: pipelined top-10, register-slimmed via 5+5 gather batches.
//  - NO forced min-waves (R5 lesson: __launch_bounds__(256,8) -> VGPR 32,
//    catastrophic scratch spill, FETCH 191->797MB, 2.1x slower).
//  - Two batches of 5 (Gb+Rb) gathers, accumulate between, sched_barrier
//    to keep batch 2 from hoisting: halves in-flight load registers.
//  - 32-bit byte-offset address math for gathers (Gb spans 38.4MB).
//  - Same cross-iteration prefetch (stage A: src/rid; stage B: score
//    gathers), rank-0-lane max, deferred softmax normalization as v5.
//  - Accumulation order k=0..9 identical to v5.
// ---------------------------------------------------------------------------
__global__ __launch_bounds__(256) void gather_topk_out(
    const int* __restrict__ src, const int* __restrict__ rel_id,
    const float* __restrict__ ssrc, const float* __restrict__ sdst,
    const float* __restrict__ srel, const ushort_t* __restrict__ Gb,
    const ushort_t* __restrict__ Rb, float* __restrict__ out)
{
    const int l         = threadIdx.x & 31;
    const int halfShift = threadIdx.x & 32;    // 0 or 32
    const uint_t tie1   = (uint_t)(31 - l);
    const char* GbC = (const char*)Gb + l * 8;  // row byte-stride 256
    const char* RbC = (const char*)Rb + l * 8;
    int hw  = (blockIdx.x * blockDim.x + threadIdx.x) >> 5;
    int nhw = (gridDim.x * blockDim.x) >> 5;

    int i = hw;
    if (i >= N_ENT) return;

    // pipeline prologue: stage A+B for first node
    int   sidx = src   [(size_t)i * DEG + l];
    int   ridx = rel_id[(size_t)i * DEG + l];
    float s1 = ssrc[sidx], s2 = sdst[i], s3 = srel[ridx];

    while (true) {
        const int inext = i + nhw;
        const int ic    = inext < N_ENT ? inext : i;   // clamped prefetch idx

        // ---- stage A(i+1): issue coalesced index loads early ----
        const size_t off2 = (size_t)ic * DEG + l;
        int sidx2 = src[off2];
        int ridx2 = rel_id[off2];

        // ---- current node: score + monotone key ----
        float x   = s1 + s2 + s3;
        float val = x >= 0.f ? x : 0.2f * x;           // leaky_relu(0.2)
        uint_t ub = __builtin_bit_cast(uint_t, val);
        uint_t mk = ub ^ (uint_t)(((int)ub >> 31) | (int)0x80000000);
        unsigned long long k1 = ((unsigned long long)mk << 5) | tie1;

        // ---- rank phase (31 shuffles) — hides stage-A latency ----
        int rank = 0;
        #pragma unroll
        for (int xm = 1; xm < 32; ++xm) {
            uint_t mk2 = (uint_t)__shfl_xor((int)mk, xm, 32);
            unsigned long long k2 =
                ((unsigned long long)mk2 << 5) | (tie1 ^ (uint_t)xm);
            rank += (k2 > k1) ? 1 : 0;
        }
        bool sel = rank < TOPK;

        // ---- stage B(i+1): issue dependent score gathers ----
        float s1n = ssrc[sidx2];
        float s2n = sdst[ic];
        float s3n = srel[ridx2];

        // ---- global max = rank-0 lane's value ----
        unsigned long long b0 = __ballot(rank == 0);
        int l0 = (int)__builtin_ctz((uint_t)(b0 >> halfShift));
        float mx = __shfl(val, l0, 32);

        float e = sel ? __expf(val - mx) : 0.f;

        // selected-lane mask for this half-wave
        unsigned long long ball = __ballot(sel);
        uint_t mask = (uint_t)(ball >> halfShift);

        uint_t packed = (uint_t)sidx | ((uint_t)ridx << 18);
        f32x2 a01 = {0.f, 0.f}, a23 = {0.f, 0.f};
        float ws = 0.f;

        // ---- batch 1: k = 0..4 ----
        {
            uint2 gv[5], rv[5]; float wk[5];
            #pragma unroll
            for (int k = 0; k < 5; ++k) {
                int lk = (int)__builtin_ctz(mask); mask &= mask - 1;
                uint_t p = (uint_t)__shfl((int)packed, lk, 32);
                wk[k] = __shfl(e, lk, 32);
                gv[k] = *(const uint2*)(GbC + (p & 0x3FFFF) * 256u);
                rv[k] = *(const uint2*)(RbC + (p >> 18) * 256u);
            }
            #pragma unroll
            for (int k = 0; k < 5; ++k) {
                float wv = wk[k];
                f32x2 g01 = unpk2(gv[k].x), g23 = unpk2(gv[k].y);
                f32x2 r01 = unpk2(rv[k].x), r23 = unpk2(rv[k].y);
                a01 += (g01 + r01) * wv;
                a23 += (g23 + r23) * wv;
                ws  += wv;
            }
        }
        __builtin_amdgcn_sched_barrier(0);   // keep batch 2 from hoisting
        // ---- batch 2: k = 5..9 ----
        {
            uint2 gv[5], rv[5]; float wk[5];
            #pragma unroll
            for (int k = 0; k < 5; ++k) {
                int lk = (int)__builtin_ctz(mask); mask &= mask - 1;
                uint_t p = (uint_t)__shfl((int)packed, lk, 32);
                wk[k] = __shfl(e, lk, 32);
                gv[k] = *(const uint2*)(GbC + (p & 0x3FFFF) * 256u);
                rv[k] = *(const uint2*)(RbC + (p >> 18) * 256u);
            }
            #pragma unroll
            for (int k = 0; k < 5; ++k) {
                float wv = wk[k];
                f32x2 g01 = unpk2(gv[k].x), g23 = unpk2(gv[k].y);
                f32x2 r01 = unpk2(rv[k].x), r23 = unpk2(rv[k].y);
                a01 += (g01 + r01) * wv;
                a23 += (g23 + r23) * wv;
                ws  += wv;
            }
        }

        float rnorm = __builtin_amdgcn_rcpf(ws);
        a01 *= rnorm; a23 *= rnorm;

        float4 o;
        o.x = fast_tanh(a01.x); o.y = fast_tanh(a01.y);
        o.z = fast_tanh(a23.x); o.w = fast_tanh(a23.y);
        ((float4*)(out + (size_t)i * H))[l] = o;

        if (inext >= N_ENT) break;
        i = inext;
        sidx = sidx2; ridx = ridx2;
        s1 = s1n; s2 = s2n; s3 = s3n;
    }
}

// ---------------------------------------------------------------------------
extern "C" void kernel_launch(void* const* d_in, const int* in_sizes, int n_in,
                              void* d_out, int out_size, void* d_ws, size_t ws_size,
                              hipStream_t stream) {
    const float* ent = (const float*)d_in[0];   // 150000x128
    const float* rel = (const float*)d_in[1];   // 500x128
    const float* W   = (const float*)d_in[2];   // 128x128
    const float* Wr  = (const float*)d_in[3];   // 128x128
    const float* a   = (const float*)d_in[4];   // 384
    const float* nw  = (const float*)d_in[5];   // 128x128
    const int*   src = (const int*)d_in[6];     // 150000x32
    const int*   rid = (const int*)d_in[7];     // 150000x32
    float* out = (float*)d_out;                 // 150000x128

    float* ws = (float*)d_ws;
    float*    M    = ws;                     // 16384
    float*    M2   = M    + 16384;           // 16384
    float*    v1   = M2   + 16384;           // 128
    float*    v2   = v1   + 128;             // 128
    float*    u3   = v2   + 128;             // 128
    float*    srel = u3   + 128;             // 512 (padded)
    float*    ssrc = srel + 512;             // 150016
    float*    sdst = ssrc + 150016;          // 150016
    ushort_t* Bhi  = (ushort_t*)(sdst + 150016);            // 16384 bf16
    ushort_t* Blo  = Bhi + 16384;                           // 16384 bf16
    ushort_t* Rb   = Blo + 16384;                           // 64000 bf16
    ushort_t* Gb   = Rb  + 64000;                           // 19.2M bf16

    precompute_small<<<H + 1, H, 0, stream>>>(W, Wr, nw, a, M, M2, v1, v2, u3);
    bfrag_build    <<<32, 64, 0, stream>>>(M, Bhi, Blo);
    rel_transform  <<<N_REL, H, 0, stream>>>(rel, M2, u3, Rb, srel);
    ent_transform3 <<<(N_ENT + 127) / 128, 256, 0, stream>>>(ent, Bhi, Blo,
                                                             v1, v2, Gb, ssrc, sdst);
    gather_topk_out<<<2048, 256, 0, stream>>>(src, rid, ssrc, sdst, srel,
                                              Gb, Rb, out);
}

// Round 10
// 315.764 us; speedup vs baseline: 1.4406x; 1.0578x over previous
//
#include <hip/hip_runtime.h>
#include <hip/hip_bf16.h>
#include <math.h>

#define N_ENT 150000
#define N_REL 500
#define H     128
#define DEG   32
#define TOPK  10

typedef unsigned short ushort_t;
typedef unsigned int   uint_t;
typedef __attribute__((ext_vector_type(8))) short short8;
typedef __attribute__((ext_vector_type(4))) float f32x4;
typedef __attribute__((ext_vector_type(2))) float f32x2;

__device__ inline ushort_t f2bf(float x) {
    __hip_bfloat16 h = __float2bfloat16(x);   // RNE
    return *reinterpret_cast<ushort_t*>(&h);
}
__device__ inline float bf2f(ushort_t u) {
    uint_t v = ((uint_t)u) << 16;
    return *reinterpret_cast<float*>(&v);
}
// unpack 2 bf16 (packed in one u32) -> 2 f32: {low ushort, high ushort}
__device__ inline f32x2 unpk2(uint_t u) {
    uint_t lo = u << 16;
    uint_t hi = u & 0xFFFF0000u;
    f32x2 r;
    r.x = *reinterpret_cast<float*>(&lo);
    r.y = *reinterpret_cast<float*>(&hi);
    return r;
}
__device__ inline float dot4(float4 a, float4 b) {
    return a.x * b.x + a.y * b.y + a.z * b.z + a.w * b.w;
}
__device__ inline float fast_tanh(float x) {
    float e = __expf(2.f * x);                 // v_exp_f32
    return 1.f - 2.f * __builtin_amdgcn_rcpf(e + 1.f);
}

// ---------------------------------------------------------------------------
// Kernel A: tiny precomputes.
// ---------------------------------------------------------------------------
__global__ __launch_bounds__(128) void precompute_small(
    const float* __restrict__ W, const float* __restrict__ Wr,
    const float* __restrict__ nw, const float* __restrict__ a,
    float* __restrict__ M, float* __restrict__ M2,
    float* __restrict__ v1, float* __restrict__ v2, float* __restrict__ u3)
{
    int j = threadIdx.x;
    if (blockIdx.x < H) {
        int r = blockIdx.x;
        float m = 0.f, m2 = 0.f;
        for (int t = 0; t < H; ++t) {
            float x = nw[t * H + j];
            m  += W [r * H + t] * x;
            m2 += Wr[r * H + t] * x;
        }
        M [r * H + j] = m;
        M2[r * H + j] = m2;
    } else {
        int h = j;
        float s1 = 0.f, s2 = 0.f, s3 = 0.f;
        for (int t = 0; t < H; ++t) {
            s1 += W [h * H + t] * a[t];
            s2 += W [h * H + t] * a[H + t];
            s3 += Wr[h * H + t] * a[2 * H + t];
        }
        v1[h] = s1; v2[h] = s2; u3[h] = s3;
    }
}

// ---------------------------------------------------------------------------
// Kernel A2: build B fragments of M in MFMA lane layout, bf16 hi/lo.
// ---------------------------------------------------------------------------
__global__ __launch_bounds__(64) void bfrag_build(
    const float* __restrict__ M, ushort_t* __restrict__ Bhi,
    ushort_t* __restrict__ Blo)
{
    int b = blockIdx.x;           // 0..31 = c*4 + t
    int c = b >> 2, tt = b & 3;
    int l = threadIdx.x;
    int n  = c * 16 + (l & 15);
    int k0 = tt * 32 + (l >> 4) * 8;
    #pragma unroll
    for (int j = 0; j < 8; ++j) {
        float x = M[(k0 + j) * H + n];
        ushort_t h = f2bf(x);
        Bhi[(size_t)(b * 64 + l) * 8 + j] = h;
        Blo[(size_t)(b * 64 + l) * 8 + j] = f2bf(x - bf2f(h));
    }
}

// ---------------------------------------------------------------------------
// Kernel B: R = rel_emb @ M2 (500x128, bf16), s_rel = rel_emb @ u3
// ---------------------------------------------------------------------------
__global__ __launch_bounds__(128) void rel_transform(
    const float* __restrict__ rel, const float* __restrict__ M2,
    const float* __restrict__ u3, ushort_t* __restrict__ Rb,
    float* __restrict__ srel)
{
    __shared__ float red[H];
    int r = blockIdx.x, j = threadIdx.x;
    float acc = 0.f;
    for (int h = 0; h < H; ++h)
        acc += rel[r * H + h] * M2[h * H + j];
    Rb[r * H + j] = f2bf(acc);
    red[j] = rel[r * H + j] * u3[j];
    __syncthreads();
    for (int s = 64; s > 0; s >>= 1) {
        if (j < s) red[j] += red[j + s];
        __syncthreads();
    }
    if (j == 0) srel[r] = red[0];
}

// ---------------------------------------------------------------------------
// Kernel C v5: G = ent @ M via bf16 hi/lo MFMA (operand-swapped layout)
// + LDS-staged coalesced output.  Compute identical to v4; the epilogue
// writes the 128x128 bf16 tile to LDS (XOR-16 swizzle: byte ^= (row&15)<<4,
// 2-way max bank aliasing = free), one barrier, then a fully-coalesced
// 16B/lane global store pass (replaces 64-lane x 8B x 256B-stride scatter).
// ---------------------------------------------------------------------------
__global__ __launch_bounds__(256) void ent_transform3(
    const float* __restrict__ ent, const ushort_t* __restrict__ Bhi,
    const ushort_t* __restrict__ Blo, const float* __restrict__ v1,
    const float* __restrict__ v2, ushort_t* __restrict__ Gb,
    float* __restrict__ ssrc, float* __restrict__ sdst)
{
    __shared__ ushort_t tile[128 * 128];   // 32 KB
    const int t    = threadIdx.x;
    const int w    = t >> 6;       // wave 0..3
    const int l    = t & 63;
    const int m    = l & 15;
    const int quad = l >> 4;
    const long blockRow = (long)blockIdx.x * 128;
    const long waveRow  = blockRow + (long)w * 32;

    float4 v1a[4], v1b[4], v2a[4], v2b[4];
    #pragma unroll
    for (int tt = 0; tt < 4; ++tt) {
        const float* p1 = v1 + tt * 32 + quad * 8;
        const float* p2 = v2 + tt * 32 + quad * 8;
        v1a[tt] = *(const float4*)p1; v1b[tt] = *(const float4*)(p1 + 4);
        v2a[tt] = *(const float4*)p2; v2b[tt] = *(const float4*)(p2 + 4);
    }

    short8 Ahi[2][4], Alo[2][4];
    float p1s[2] = {0.f, 0.f}, p2s[2] = {0.f, 0.f};
    #pragma unroll
    for (int s = 0; s < 2; ++s) {
        long row = waveRow + s * 16 + m;
        long rc  = row < N_ENT ? row : (N_ENT - 1);
        const float* rp = ent + rc * H;
        #pragma unroll
        for (int tt = 0; tt < 4; ++tt) {
            float4 e0 = *(const float4*)(rp + tt * 32 + quad * 8);
            float4 e1 = *(const float4*)(rp + tt * 32 + quad * 8 + 4);
            p1s[s] += dot4(e0, v1a[tt]) + dot4(e1, v1b[tt]);
            p2s[s] += dot4(e0, v2a[tt]) + dot4(e1, v2b[tt]);
            float x[8] = {e0.x, e0.y, e0.z, e0.w, e1.x, e1.y, e1.z, e1.w};
            #pragma unroll
            for (int j = 0; j < 8; ++j) {
                ushort_t h = f2bf(x[j]);
                Ahi[s][tt][j] = (short)h;
                Alo[s][tt][j] = (short)f2bf(x[j] - bf2f(h));
            }
        }
    }
    #pragma unroll
    for (int s = 0; s < 2; ++s) {
        p1s[s] += __shfl_xor(p1s[s], 16); p1s[s] += __shfl_xor(p1s[s], 32);
        p2s[s] += __shfl_xor(p2s[s], 16); p2s[s] += __shfl_xor(p2s[s], 32);
    }
    if (quad == 0) {
        #pragma unroll
        for (int s = 0; s < 2; ++s) {
            long row = waveRow + s * 16 + m;
            if (row < N_ENT) { ssrc[row] = p1s[s]; sdst[row] = p2s[s]; }
        }
    }

    for (int c = 0; c < 8; ++c) {
        short8 bh[4], bl[4];
        #pragma unroll
        for (int tt = 0; tt < 4; ++tt) {
            size_t off = (size_t)((c * 4 + tt) * 64 + l) * 8;
            bh[tt] = *(const short8*)(Bhi + off);
            bl[tt] = *(const short8*)(Blo + off);
        }
        f32x4 acc0 = {0.f, 0.f, 0.f, 0.f}, acc1 = {0.f, 0.f, 0.f, 0.f};
        #pragma unroll
        for (int tt = 0; tt < 4; ++tt) {
            acc0 = __builtin_amdgcn_mfma_f32_16x16x32_bf16(bh[tt], Ahi[0][tt], acc0, 0, 0, 0);
            acc0 = __builtin_amdgcn_mfma_f32_16x16x32_bf16(bh[tt], Alo[0][tt], acc0, 0, 0, 0);
            acc0 = __builtin_amdgcn_mfma_f32_16x16x32_bf16(bl[tt], Ahi[0][tt], acc0, 0, 0, 0);
            acc1 = __builtin_amdgcn_mfma_f32_16x16x32_bf16(bh[tt], Ahi[1][tt], acc1, 0, 0, 0);
            acc1 = __builtin_amdgcn_mfma_f32_16x16x32_bf16(bh[tt], Alo[1][tt], acc1, 0, 0, 0);
            acc1 = __builtin_amdgcn_mfma_f32_16x16x32_bf16(bl[tt], Ahi[1][tt], acc1, 0, 0, 0);
        }
        #pragma unroll
        for (int s = 0; s < 2; ++s) {
            f32x4 a = s ? acc1 : acc0;
            int ldsrow = w * 32 + s * 16 + m;        // ldsrow & 15 == m
            uint_t cb = (uint_t)(c * 32 + quad * 8) ^ ((uint_t)(m & 15) << 4);
            ushort4 o;
            o.x = f2bf(a[0]); o.y = f2bf(a[1]);
            o.z = f2bf(a[2]); o.w = f2bf(a[3]);
            *(ushort4*)((char*)tile + ldsrow * 256 + cb) = o;
        }
    }
    __syncthreads();

    // coalesced store pass: 8 reps x 256 threads x 16B = 32 KB
    #pragma unroll
    for (int rep = 0; rep < 8; ++rep) {
        int idx   = rep * 256 + t;       // 0..2047
        int r     = idx >> 4;            // lds row 0..127
        int chunk = idx & 15;            // 16B chunk within row
        uint4 v = *(const uint4*)((char*)tile + r * 256 +
                                  ((chunk * 16) ^ ((r & 15) << 4)));
        long row = blockRow + r;
        if (row < N_ENT)
            *(uint4*)((char*)Gb + (size_t)row * 256 + chunk * 16) = v;
    }
}

// ---------------------------------------------------------------------------
// Kernel D v5 (restored verbatim — proven 126.9 us anchor):
// pipelined top-10; all 20 gathers batched (ILP > TLP: v7's 5+5 split with
// higher occupancy was 144.6 us; v5's deep batch at occ 28% was 126.9).
// ---------------------------------------------------------------------------
__global__ __launch_bounds__(256) void gather_topk_out(
    const int* __restrict__ src, const int* __restrict__ rel_id,
    const float* __restrict__ ssrc, const float* __restrict__ sdst,
    const float* __restrict__ srel, const ushort_t* __restrict__ Gb,
    const ushort_t* __restrict__ Rb, float* __restrict__ out)
{
    const int l         = threadIdx.x & 31;
    const int halfShift = threadIdx.x & 32;    // 0 or 32
    const uint_t tie1   = (uint_t)(31 - l);
    const ushort_t* GbL = Gb + l * 4;
    const ushort_t* RbL = Rb + l * 4;
    int hw  = (blockIdx.x * blockDim.x + threadIdx.x) >> 5;
    int nhw = (gridDim.x * blockDim.x) >> 5;

    int i = hw;
    if (i >= N_ENT) return;

    // pipeline prologue: stage A+B for first node
    int   sidx = src   [(size_t)i * DEG + l];
    int   ridx = rel_id[(size_t)i * DEG + l];
    float s1 = ssrc[sidx], s2 = sdst[i], s3 = srel[ridx];

    while (true) {
        const int inext = i + nhw;
        const int ic    = inext < N_ENT ? inext : i;   // clamped prefetch idx

        // ---- stage A(i+1): issue coalesced index loads early ----
        const size_t off2 = (size_t)ic * DEG + l;
        int sidx2 = src[off2];
        int ridx2 = rel_id[off2];

        // ---- current node: score + monotone key ----
        float x   = s1 + s2 + s3;
        float val = x >= 0.f ? x : 0.2f * x;           // leaky_relu(0.2)
        uint_t ub = __builtin_bit_cast(uint_t, val);
        uint_t mk = ub ^ (uint_t)(((int)ub >> 31) | (int)0x80000000);
        unsigned long long k1 = ((unsigned long long)mk << 5) | tie1;

        // ---- rank phase (31 shuffles) — hides stage-A latency ----
        int rank = 0;
        #pragma unroll
        for (int xm = 1; xm < 32; ++xm) {
            uint_t mk2 = (uint_t)__shfl_xor((int)mk, xm, 32);
            unsigned long long k2 =
                ((unsigned long long)mk2 << 5) | (tie1 ^ (uint_t)xm);
            rank += (k2 > k1) ? 1 : 0;
        }
        bool sel = rank < TOPK;

        // ---- stage B(i+1): issue dependent score gathers ----
        float s1n = ssrc[sidx2];
        float s2n = sdst[ic];
        float s3n = srel[ridx2];

        // ---- global max = rank-0 lane's value ----
        unsigned long long b0 = __ballot(rank == 0);
        int l0 = (int)__builtin_ctz((uint_t)(b0 >> halfShift));
        float mx = __shfl(val, l0, 32);

        float e = sel ? __expf(val - mx) : 0.f;

        // selected-lane mask for this half-wave
        unsigned long long ball = __ballot(sel);
        uint_t mask = (uint_t)(ball >> halfShift);

        // broadcast + load-issue fused: packed idx consumed immediately
        uint_t packed = (uint_t)sidx | ((uint_t)ridx << 18);
        uint2 gv[TOPK], rv[TOPK]; float wk[TOPK];
        #pragma unroll
        for (int k = 0; k < TOPK; ++k) {
            int lk = (int)__builtin_ctz(mask); mask &= mask - 1;
            uint_t p = (uint_t)__shfl((int)packed, lk, 32);
            wk[k] = __shfl(e, lk, 32);
            gv[k] = *(const uint2*)(GbL + (size_t)(p & 0x3FFFF) * H);
            rv[k] = *(const uint2*)(RbL + (size_t)(p >> 18) * H);
        }
        float ws = ((wk[0] + wk[1]) + (wk[2] + wk[3]))
                 + ((wk[4] + wk[5]) + (wk[6] + wk[7]))
                 + (wk[8] + wk[9]);
        float rnorm = __builtin_amdgcn_rcpf(ws);

        f32x2 a01 = {0.f, 0.f}, a23 = {0.f, 0.f};
        #pragma unroll
        for (int k = 0; k < TOPK; ++k) {
            float wv = wk[k];
            f32x2 g01 = unpk2(gv[k].x), g23 = unpk2(gv[k].y);
            f32x2 r01 = unpk2(rv[k].x), r23 = unpk2(rv[k].y);
            a01 += (g01 + r01) * wv;
            a23 += (g23 + r23) * wv;
        }
        a01 *= rnorm; a23 *= rnorm;

        float4 o;
        o.x = fast_tanh(a01.x); o.y = fast_tanh(a01.y);
        o.z = fast_tanh(a23.x); o.w = fast_tanh(a23.y);
        ((float4*)(out + (size_t)i * H))[l] = o;

        if (inext >= N_ENT) break;
        i = inext;
        sidx = sidx2; ridx = ridx2;
        s1 = s1n; s2 = s2n; s3 = s3n;
    }
}

// ---------------------------------------------------------------------------
extern "C" void kernel_launch(void* const* d_in, const int* in_sizes, int n_in,
                              void* d_out, int out_size, void* d_ws, size_t ws_size,
                              hipStream_t stream) {
    const float* ent = (const float*)d_in[0];   // 150000x128
    const float* rel = (const float*)d_in[1];   // 500x128
    const float* W   = (const float*)d_in[2];   // 128x128
    const float* Wr  = (const float*)d_in[3];   // 128x128
    const float* a   = (const float*)d_in[4];   // 384
    const float* nw  = (const float*)d_in[5];   // 128x128
    const int*   src = (const int*)d_in[6];     // 150000x32
    const int*   rid = (const int*)d_in[7];     // 150000x32
    float* out = (float*)d_out;                 // 150000x128

    float* ws = (float*)d_ws;
    float*    M    = ws;                     // 16384
    float*    M2   = M    + 16384;           // 16384
    float*    v1   = M2   + 16384;           // 128
    float*    v2   = v1   + 128;             // 128
    float*    u3   = v2   + 128;             // 128
    float*    srel = u3   + 128;             // 512 (padded)
    float*    ssrc = srel + 512;             // 150016
    float*    sdst = ssrc + 150016;          // 150016
    ushort_t* Bhi  = (ushort_t*)(sdst + 150016);            // 16384 bf16
    ushort_t* Blo  = Bhi + 16384;                           // 16384 bf16
    ushort_t* Rb   = Blo + 16384;                           // 64000 bf16
    ushort_t* Gb   = Rb  + 64000;                           // 19.2M bf16

    precompute_small<<<H + 1, H, 0, stream>>>(W, Wr, nw, a, M, M2, v1, v2, u3);
    bfrag_build    <<<32, 64, 0, stream>>>(M, Bhi, Blo);
    rel_transform  <<<N_REL, H, 0, stream>>>(rel, M2, u3, Rb, srel);
    ent_transform3 <<<(N_ENT + 127) / 128, 256, 0, stream>>>(ent, Bhi, Blo,
                                                             v1, v2, Gb, ssrc, sdst);
    gather_topk_out<<<2048, 256, 0, stream>>>(src, rid, ssrc, sdst, srel,
                                              Gb, Rb, out);
}

// Round 15
// 307.444 us; speedup vs baseline: 1.4796x; 1.0271x over previous
//
#include <hip/hip_runtime.h>
#include <hip/hip_bf16.h>
#include <math.h>

#define N_ENT 150000
#define N_REL 500
#define H     128
#define DEG   32
#define TOPK  10

typedef unsigned short ushort_t;
typedef unsigned int   uint_t;
typedef __attribute__((ext_vector_type(8))) short short8;
typedef __attribute__((ext_vector_type(4))) float f32x4;
typedef __attribute__((ext_vector_type(2))) float f32x2;

__device__ inline ushort_t f2bf(float x) {
    __hip_bfloat16 h = __float2bfloat16(x);   // RNE
    return *reinterpret_cast<ushort_t*>(&h);
}
__device__ inline float bf2f(ushort_t u) {
    uint_t v = ((uint_t)u) << 16;
    return *reinterpret_cast<float*>(&v);
}
// unpack 2 bf16 (packed in one u32) -> 2 f32: {low ushort, high ushort}
__device__ inline f32x2 unpk2(uint_t u) {
    uint_t lo = u << 16;
    uint_t hi = u & 0xFFFF0000u;
    f32x2 r;
    r.x = *reinterpret_cast<float*>(&lo);
    r.y = *reinterpret_cast<float*>(&hi);
    return r;
}
__device__ inline float dot4(float4 a, float4 b) {
    return a.x * b.x + a.y * b.y + a.z * b.z + a.w * b.w;
}
__device__ inline float fast_tanh(float x) {
    float e = __expf(2.f * x);                 // v_exp_f32
    return 1.f - 2.f * __builtin_amdgcn_rcpf(e + 1.f);
}

// ---------------------------------------------------------------------------
// Kernel A: tiny precomputes.
// ---------------------------------------------------------------------------
__global__ __launch_bounds__(128) void precompute_small(
    const float* __restrict__ W, const float* __restrict__ Wr,
    const float* __restrict__ nw, const float* __restrict__ a,
    float* __restrict__ M, float* __restrict__ M2,
    float* __restrict__ v1, float* __restrict__ v2, float* __restrict__ u3)
{
    int j = threadIdx.x;
    if (blockIdx.x < H) {
        int r = blockIdx.x;
        float m = 0.f, m2 = 0.f;
        for (int t = 0; t < H; ++t) {
            float x = nw[t * H + j];
            m  += W [r * H + t] * x;
            m2 += Wr[r * H + t] * x;
        }
        M [r * H + j] = m;
        M2[r * H + j] = m2;
    } else {
        int h = j;
        float s1 = 0.f, s2 = 0.f, s3 = 0.f;
        for (int t = 0; t < H; ++t) {
            s1 += W [h * H + t] * a[t];
            s2 += W [h * H + t] * a[H + t];
            s3 += Wr[h * H + t] * a[2 * H + t];
        }
        v1[h] = s1; v2[h] = s2; u3[h] = s3;
    }
}

// ---------------------------------------------------------------------------
// Kernel A2: build B fragments of M in MFMA lane layout, bf16 hi/lo.
// ---------------------------------------------------------------------------
__global__ __launch_bounds__(64) void bfrag_build(
    const float* __restrict__ M, ushort_t* __restrict__ Bhi,
    ushort_t* __restrict__ Blo)
{
    int b = blockIdx.x;           // 0..31 = c*4 + t
    int c = b >> 2, tt = b & 3;
    int l = threadIdx.x;
    int n  = c * 16 + (l & 15);
    int k0 = tt * 32 + (l >> 4) * 8;
    #pragma unroll
    for (int j = 0; j < 8; ++j) {
        float x = M[(k0 + j) * H + n];
        ushort_t h = f2bf(x);
        Bhi[(size_t)(b * 64 + l) * 8 + j] = h;
        Blo[(size_t)(b * 64 + l) * 8 + j] = f2bf(x - bf2f(h));
    }
}

// ---------------------------------------------------------------------------
// Kernel B: R = rel_emb @ M2 (500x128, bf16), s_rel = rel_emb @ u3
// ---------------------------------------------------------------------------
__global__ __launch_bounds__(128) void rel_transform(
    const float* __restrict__ rel, const float* __restrict__ M2,
    const float* __restrict__ u3, ushort_t* __restrict__ Rb,
    float* __restrict__ srel)
{
    __shared__ float red[H];
    int r = blockIdx.x, j = threadIdx.x;
    float acc = 0.f;
    for (int h = 0; h < H; ++h)
        acc += rel[r * H + h] * M2[h * H + j];
    Rb[r * H + j] = f2bf(acc);
    red[j] = rel[r * H + j] * u3[j];
    __syncthreads();
    for (int s = 64; s > 0; s >>= 1) {
        if (j < s) red[j] += red[j + s];
        __syncthreads();
    }
    if (j == 0) srel[r] = red[0];
}

// ---------------------------------------------------------------------------
// Kernel C v5: G = ent @ M via bf16 hi/lo MFMA (operand-swapped layout)
// + LDS-staged coalesced output (confirmed −11us on residual, R10).
// ---------------------------------------------------------------------------
__global__ __launch_bounds__(256) void ent_transform3(
    const float* __restrict__ ent, const ushort_t* __restrict__ Bhi,
    const ushort_t* __restrict__ Blo, const float* __restrict__ v1,
    const float* __restrict__ v2, ushort_t* __restrict__ Gb,
    float* __restrict__ ssrc, float* __restrict__ sdst)
{
    __shared__ ushort_t tile[128 * 128];   // 32 KB
    const int t    = threadIdx.x;
    const int w    = t >> 6;       // wave 0..3
    const int l    = t & 63;
    const int m    = l & 15;
    const int quad = l >> 4;
    const long blockRow = (long)blockIdx.x * 128;
    const long waveRow  = blockRow + (long)w * 32;

    float4 v1a[4], v1b[4], v2a[4], v2b[4];
    #pragma unroll
    for (int tt = 0; tt < 4; ++tt) {
        const float* p1 = v1 + tt * 32 + quad * 8;
        const float* p2 = v2 + tt * 32 + quad * 8;
        v1a[tt] = *(const float4*)p1; v1b[tt] = *(const float4*)(p1 + 4);
        v2a[tt] = *(const float4*)p2; v2b[tt] = *(const float4*)(p2 + 4);
    }

    short8 Ahi[2][4], Alo[2][4];
    float p1s[2] = {0.f, 0.f}, p2s[2] = {0.f, 0.f};
    #pragma unroll
    for (int s = 0; s < 2; ++s) {
        long row = waveRow + s * 16 + m;
        long rc  = row < N_ENT ? row : (N_ENT - 1);
        const float* rp = ent + rc * H;
        #pragma unroll
        for (int tt = 0; tt < 4; ++tt) {
            float4 e0 = *(const float4*)(rp + tt * 32 + quad * 8);
            float4 e1 = *(const float4*)(rp + tt * 32 + quad * 8 + 4);
            p1s[s] += dot4(e0, v1a[tt]) + dot4(e1, v1b[tt]);
            p2s[s] += dot4(e0, v2a[tt]) + dot4(e1, v2b[tt]);
            float x[8] = {e0.x, e0.y, e0.z, e0.w, e1.x, e1.y, e1.z, e1.w};
            #pragma unroll
            for (int j = 0; j < 8; ++j) {
                ushort_t h = f2bf(x[j]);
                Ahi[s][tt][j] = (short)h;
                Alo[s][tt][j] = (short)f2bf(x[j] - bf2f(h));
            }
        }
    }
    #pragma unroll
    for (int s = 0; s < 2; ++s) {
        p1s[s] += __shfl_xor(p1s[s], 16); p1s[s] += __shfl_xor(p1s[s], 32);
        p2s[s] += __shfl_xor(p2s[s], 16); p2s[s] += __shfl_xor(p2s[s], 32);
    }
    if (quad == 0) {
        #pragma unroll
        for (int s = 0; s < 2; ++s) {
            long row = waveRow + s * 16 + m;
            if (row < N_ENT) { ssrc[row] = p1s[s]; sdst[row] = p2s[s]; }
        }
    }

    for (int c = 0; c < 8; ++c) {
        short8 bh[4], bl[4];
        #pragma unroll
        for (int tt = 0; tt < 4; ++tt) {
            size_t off = (size_t)((c * 4 + tt) * 64 + l) * 8;
            bh[tt] = *(const short8*)(Bhi + off);
            bl[tt] = *(const short8*)(Blo + off);
        }
        f32x4 acc0 = {0.f, 0.f, 0.f, 0.f}, acc1 = {0.f, 0.f, 0.f, 0.f};
        #pragma unroll
        for (int tt = 0; tt < 4; ++tt) {
            acc0 = __builtin_amdgcn_mfma_f32_16x16x32_bf16(bh[tt], Ahi[0][tt], acc0, 0, 0, 0);
            acc0 = __builtin_amdgcn_mfma_f32_16x16x32_bf16(bh[tt], Alo[0][tt], acc0, 0, 0, 0);
            acc0 = __builtin_amdgcn_mfma_f32_16x16x32_bf16(bl[tt], Ahi[0][tt], acc0, 0, 0, 0);
            acc1 = __builtin_amdgcn_mfma_f32_16x16x32_bf16(bh[tt], Ahi[1][tt], acc1, 0, 0, 0);
            acc1 = __builtin_amdgcn_mfma_f32_16x16x32_bf16(bh[tt], Alo[1][tt], acc1, 0, 0, 0);
            acc1 = __builtin_amdgcn_mfma_f32_16x16x32_bf16(bl[tt], Ahi[1][tt], acc1, 0, 0, 0);
        }
        #pragma unroll
        for (int s = 0; s < 2; ++s) {
            f32x4 a = s ? acc1 : acc0;
            int ldsrow = w * 32 + s * 16 + m;        // ldsrow & 15 == m
            uint_t cb = (uint_t)(c * 32 + quad * 8) ^ ((uint_t)(m & 15) << 4);
            ushort4 o;
            o.x = f2bf(a[0]); o.y = f2bf(a[1]);
            o.z = f2bf(a[2]); o.w = f2bf(a[3]);
            *(ushort4*)((char*)tile + ldsrow * 256 + cb) = o;
        }
    }
    __syncthreads();

    // coalesced store pass: 8 reps x 256 threads x 16B = 32 KB
    #pragma unroll
    for (int rep = 0; rep < 8; ++rep) {
        int idx   = rep * 256 + t;       // 0..2047
        int r     = idx >> 4;            // lds row 0..127
        int chunk = idx & 15;            // 16B chunk within row
        uint4 v = *(const uint4*)((char*)tile + r * 256 +
                                  ((chunk * 16) ^ ((r & 15) << 4)));
        long row = blockRow + r;
        if (row < N_ENT)
            *(uint4*)((char*)Gb + (size_t)row * 256 + chunk * 16) = v;
    }
}

// ---------------------------------------------------------------------------
// Kernel D — TRUE v5 (R3-submission structure, 126.9 us @ R4 bench):
// separate broadcast loop (pk[]/wk[]) then ALL Gb loads batched, then all
// Rb loads, then accumulate.  ILP > TLP: fused broadcast+load (R10: 136us,
// VGPR 56, occ 41%) and 5+5 split (R6: 144us) both lose to this (VGPR 76,
// occ 28%) — keep the 20-row gather window fully in flight.
// ---------------------------------------------------------------------------
__global__ __launch_bounds__(256) void gather_topk_out(
    const int* __restrict__ src, const int* __restrict__ rel_id,
    const float* __restrict__ ssrc, const float* __restrict__ sdst,
    const float* __restrict__ srel, const ushort_t* __restrict__ Gb,
    const ushort_t* __restrict__ Rb, float* __restrict__ out)
{
    const int l         = threadIdx.x & 31;
    const int halfShift = threadIdx.x & 32;    // 0 or 32
    const uint_t tie1   = (uint_t)(31 - l);
    const ushort_t* GbL = Gb + l * 4;
    const ushort_t* RbL = Rb + l * 4;
    int hw  = (blockIdx.x * blockDim.x + threadIdx.x) >> 5;
    int nhw = (gridDim.x * blockDim.x) >> 5;

    int i = hw;
    if (i >= N_ENT) return;

    // pipeline prologue: stage A+B for first node
    int   sidx = src   [(size_t)i * DEG + l];
    int   ridx = rel_id[(size_t)i * DEG + l];
    float s1 = ssrc[sidx], s2 = sdst[i], s3 = srel[ridx];

    while (true) {
        const int inext = i + nhw;
        const int ic    = inext < N_ENT ? inext : i;   // clamped prefetch idx

        // ---- stage A(i+1): issue coalesced index loads early ----
        const size_t off2 = (size_t)ic * DEG + l;
        int sidx2 = src[off2];
        int ridx2 = rel_id[off2];

        // ---- current node: score + monotone key ----
        float x   = s1 + s2 + s3;
        float val = x >= 0.f ? x : 0.2f * x;           // leaky_relu(0.2)
        uint_t ub = __builtin_bit_cast(uint_t, val);
        uint_t mk = ub ^ (uint_t)(((int)ub >> 31) | (int)0x80000000);
        unsigned long long k1 = ((unsigned long long)mk << 5) | tie1;

        // ---- rank phase (31 shuffles) — hides stage-A latency ----
        int rank = 0;
        #pragma unroll
        for (int xm = 1; xm < 32; ++xm) {
            uint_t mk2 = (uint_t)__shfl_xor((int)mk, xm, 32);
            unsigned long long k2 =
                ((unsigned long long)mk2 << 5) | (tie1 ^ (uint_t)xm);
            rank += (k2 > k1) ? 1 : 0;
        }
        bool sel = rank < TOPK;

        // ---- stage B(i+1): issue dependent score gathers ----
        float s1n = ssrc[sidx2];
        float s2n = sdst[ic];
        float s3n = srel[ridx2];

        // ---- global max = rank-0 lane's value ----
        unsigned long long b0 = __ballot(rank == 0);
        int l0 = (int)__builtin_ctz((uint_t)(b0 >> halfShift));
        float mx = __shfl(val, l0, 32);

        float e = sel ? __expf(val - mx) : 0.f;

        // selected-lane mask for this half-wave
        unsigned long long ball = __ballot(sel);
        uint_t mask = (uint_t)(ball >> halfShift);

        // broadcast 10 tuples: packed idx + raw weight (2 shuffles per k)
        uint_t packed = (uint_t)sidx | ((uint_t)ridx << 18);
        uint_t pk[TOPK]; float wk[TOPK];
        #pragma unroll
        for (int k = 0; k < TOPK; ++k) {
            int lk = (int)__builtin_ctz(mask); mask &= mask - 1;
            pk[k] = (uint_t)__shfl((int)packed, lk, 32);
            wk[k] = __shfl(e, lk, 32);
        }
        float ws = ((wk[0] + wk[1]) + (wk[2] + wk[3]))
                 + ((wk[4] + wk[5]) + (wk[6] + wk[7]))
                 + (wk[8] + wk[9]);
        float rnorm = __builtin_amdgcn_rcpf(ws);

        // batch gathers: all Gb first, then Rb — 20 rows in flight
        uint2 gv[TOPK], rv[TOPK];
        #pragma unroll
        for (int k = 0; k < TOPK; ++k)
            gv[k] = *(const uint2*)(GbL + (size_t)(pk[k] & 0x3FFFF) * H);
        #pragma unroll
        for (int k = 0; k < TOPK; ++k)
            rv[k] = *(const uint2*)(RbL + (size_t)(pk[k] >> 18) * H);

        f32x2 a01 = {0.f, 0.f}, a23 = {0.f, 0.f};
        #pragma unroll
        for (int k = 0; k < TOPK; ++k) {
            float wv = wk[k];
            f32x2 g01 = unpk2(gv[k].x), g23 = unpk2(gv[k].y);
            f32x2 r01 = unpk2(rv[k].x), r23 = unpk2(rv[k].y);
            a01 += (g01 + r01) * wv;
            a23 += (g23 + r23) * wv;
        }
        a01 *= rnorm; a23 *= rnorm;

        float4 o;
        o.x = fast_tanh(a01.x); o.y = fast_tanh(a01.y);
        o.z = fast_tanh(a23.x); o.w = fast_tanh(a23.y);
        ((float4*)(out + (size_t)i * H))[l] = o;

        if (inext >= N_ENT) break;
        i = inext;
        sidx = sidx2; ridx = ridx2;
        s1 = s1n; s2 = s2n; s3 = s3n;
    }
}

// ---------------------------------------------------------------------------
extern "C" void kernel_launch(void* const* d_in, const int* in_sizes, int n_in,
                              void* d_out, int out_size, void* d_ws, size_t ws_size,
                              hipStream_t stream) {
    const float* ent = (const float*)d_in[0];   // 150000x128
    const float* rel = (const float*)d_in[1];   // 500x128
    const float* W   = (const float*)d_in[2];   // 128x128
    const float* Wr  = (const float*)d_in[3];   // 128x128
    const float* a   = (const float*)d_in[4];   // 384
    const float* nw  = (const float*)d_in[5];   // 128x128
    const int*   src = (const int*)d_in[6];     // 150000x32
    const int*   rid = (const int*)d_in[7];     // 150000x32
    float* out = (float*)d_out;                 // 150000x128

    float* ws = (float*)d_ws;
    float*    M    = ws;                     // 16384
    float*    M2   = M    + 16384;           // 16384
    float*    v1   = M2   + 16384;           // 128
    float*    v2   = v1   + 128;             // 128
    float*    u3   = v2   + 128;             // 128
    float*    srel = u3   + 128;             // 512 (padded)
    float*    ssrc = srel + 512;             // 150016
    float*    sdst = ssrc + 150016;          // 150016
    ushort_t* Bhi  = (ushort_t*)(sdst + 150016);            // 16384 bf16
    ushort_t* Blo  = Bhi + 16384;                           // 16384 bf16
    ushort_t* Rb   = Blo + 16384;                           // 64000 bf16
    ushort_t* Gb   = Rb  + 64000;                           // 19.2M bf16

    precompute_small<<<H + 1, H, 0, stream>>>(W, Wr, nw, a, M, M2, v1, v2, u3);
    bfrag_build    <<<32, 64, 0, stream>>>(M, Bhi, Blo);
    rel_transform  <<<N_REL, H, 0, stream>>>(rel, M2, u3, Rb, srel);
    ent_transform3 <<<(N_ENT + 127) / 128, 256, 0, stream>>>(ent, Bhi, Blo,
                                                             v1, v2, Gb, ssrc, sdst);
    gather_topk_out<<<2048, 256, 0, stream>>>(src, rid, ssrc, sdst, srel,
                                              Gb, Rb, out);
}